// Round 1
// baseline (179643.958 us; speedup 1.0000x reference)
//
#include <hip/hip_runtime.h>

// Persistent-LSTM kernel for MI355X.
// 256 blocks x 256 threads, 1 block/CU (VGPR-forced via __launch_bounds__(256,1):
// 64xfloat4 W_hh regs/lane ≈ 350 VGPRs > 256 -> exactly 1 wave/SIMD, 1 block/CU,
// so all 256 blocks are co-resident and the custom spin barrier cannot deadlock).
//
// Block b owns h-indices [8b,8b+8); wave w owns j0=8b+2w, j0+1 with all 4 gates
// (rows g*2048+j0+k). Column partition: lane ln owns float4 chunks {ln+64k, k=0..7}
// (cols 4*(ln+64k)..+4) -> contiguous wave-level global loads and conflict-free
// ds_read_b128 / ds_write_b128.
//
// Cross-XCD h broadcast: agent-scope relaxed atomics (sc1 -> bypass non-coherent
// per-XCD L2, resolve at Infinity Cache). Barrier: 8 leaf counters in ws (256 B
// apart), 128 arrivals (256 blocks x 4 waves) per leaf per step, release-RMW
// arrive, wave0 polls all 8 leaves with lanes 0..7 + ballot, then acquire fence.
// ws is poisoned 0xAA each launch -> leaves start at 0xAAAAAAAA; blocks 0..7
// reset their leaf to 0, everyone spin-waits for leaf < RESET_TH before arriving.

#define H      2048
#define TSTEPS 8192
#define FEAT   128
#define NBLK   256
#define NTHR   256
#define RESET_TH 0x10000000u

__device__ __forceinline__ float sigm(float xv) {
  return __builtin_amdgcn_rcpf(1.0f + __expf(-xv));
}
__device__ __forceinline__ float tanh_(float xv) {
  // 1 - 2/(e^{2x}+1): saturates correctly at +-1 for large |x| (inf-safe).
  return 1.0f - 2.0f * __builtin_amdgcn_rcpf(__expf(2.0f * xv) + 1.0f);
}

union F2U { unsigned long long u; float2 f; };

__global__ __launch_bounds__(NTHR, 1)
void lstm_persist(const float* __restrict__ x,
                  const float* __restrict__ W_ih,
                  const float* __restrict__ W_hh,
                  const float* __restrict__ b_ih,
                  const float* __restrict__ b_hh,
                  const float* __restrict__ W_lin,
                  const float* __restrict__ b_lin,
                  const float* __restrict__ W_out,
                  const float* __restrict__ b_out,
                  float* __restrict__ out,
                  float* __restrict__ ws)
{
  const int tid = threadIdx.x;
  const int b   = blockIdx.x;
  const int wv  = tid >> 6;
  const int ln  = tid & 63;

  float* hbuf0 = ws;            // [2048] ping
  float* hbuf1 = ws + H;        // [2048] pong
  float* ylin  = ws + 2 * H;    // [2048] first-linear output
  unsigned* leaves = (unsigned*)(ws + 4 * H);   // 8 counters, 64 uints apart
  unsigned* myleaf = leaves + (b & 7) * 64;

  __shared__ __align__(16) float h_lds[2][H];

  // ---- barrier-leaf reset (ws re-poisoned to 0xAA every launch) ----
  if (tid == 0 && b < 8) {
    if (__hip_atomic_load(leaves + b * 64, __ATOMIC_RELAXED,
                          __HIP_MEMORY_SCOPE_AGENT) >= RESET_TH)
      __hip_atomic_store(leaves + b * 64, 0u, __ATOMIC_RELAXED,
                         __HIP_MEMORY_SCOPE_AGENT);
  }
  if (ln == 0) {
    while (__hip_atomic_load(myleaf, __ATOMIC_RELAXED,
                             __HIP_MEMORY_SCOPE_AGENT) >= RESET_TH) {}
  }

  // ---- load persistent weights into registers ----
  const int j0 = b * 8 + wv * 2;
  float4 w[8][8];   // [g*2+k][chunk] : 256 VGPRs of W_hh
  float2 wih[8];    // W_ih slice, cols 2ln..2ln+1
  float  bias[8];   // b_ih + b_hh
  #pragma unroll
  for (int g = 0; g < 4; ++g) {
    #pragma unroll
    for (int k = 0; k < 2; ++k) {
      const int r   = g * 2 + k;
      const int row = g * H + j0 + k;          // gate-major rows [i,f,g,o]
      const float* wr = W_hh + (long)row * H;
      #pragma unroll
      for (int c = 0; c < 8; ++c)
        w[r][c] = *(const float4*)(wr + 4 * (ln + 64 * c));
      wih[r]  = *(const float2*)(W_ih + (long)row * FEAT + 2 * ln);
      bias[r] = b_ih[row] + b_hh[row];
    }
  }

  // ---- init h0 = 0 and arrive (counts as arrival #1 per wave) ----
  if (ln == 0) {
    F2U z; z.f = make_float2(0.0f, 0.0f);
    __hip_atomic_store((unsigned long long*)(hbuf0 + j0), z.u,
                       __ATOMIC_RELAXED, __HIP_MEMORY_SCOPE_AGENT);
    __hip_atomic_fetch_add(myleaf, 1u, __ATOMIC_RELEASE,
                           __HIP_MEMORY_SCOPE_AGENT);
  }

  float c0 = 0.0f, c1 = 0.0f;
  float2 xr = *(const float2*)(x + 2 * ln);   // prefetch x row 0

  #pragma unroll 1
  for (int t = 0; t < TSTEPS; ++t) {
    const float* hsrc = (t & 1) ? hbuf1 : hbuf0;
    float4 hv[8];

    if (wv == 0) {
      // wait for all 1024 waves to have produced h_t
      const unsigned target = 128u * (unsigned)(t + 1);
      const unsigned* lp = leaves + (ln & 7) * 64;
      while (true) {
        unsigned v = __hip_atomic_load(lp, __ATOMIC_RELAXED,
                                       __HIP_MEMORY_SCOPE_AGENT);
        if (__all(v >= target)) break;
      }
      __builtin_amdgcn_fence(__ATOMIC_ACQUIRE, "agent");
      // stage h_t (8 KiB) into LDS; keep own copy in regs
      #pragma unroll
      for (int k = 0; k < 8; ++k) {
        F2U lo, hi;
        const float* p = hsrc + 4 * (ln + 64 * k);
        lo.u = __hip_atomic_load((const unsigned long long*)p,
                                 __ATOMIC_RELAXED, __HIP_MEMORY_SCOPE_AGENT);
        hi.u = __hip_atomic_load((const unsigned long long*)(p + 2),
                                 __ATOMIC_RELAXED, __HIP_MEMORY_SCOPE_AGENT);
        hv[k] = make_float4(lo.f.x, lo.f.y, hi.f.x, hi.f.y);
        *(float4*)&h_lds[t & 1][4 * (ln + 64 * k)] = hv[k];
      }
    }
    __syncthreads();
    if (wv != 0) {
      #pragma unroll
      for (int k = 0; k < 8; ++k)
        hv[k] = *(const float4*)&h_lds[t & 1][4 * (ln + 64 * k)];
    }

    // x-projection partial (2 cols) + recurrent matvec partial (32 cols)
    float acc[8];
    #pragma unroll
    for (int r = 0; r < 8; ++r)
      acc[r] = wih[r].x * xr.x + wih[r].y * xr.y;

    #pragma unroll
    for (int k = 0; k < 8; ++k) {
      const float4 h4 = hv[k];
      #pragma unroll
      for (int r = 0; r < 8; ++r) {
        const float4 w4 = w[r][k];
        acc[r] += w4.x * h4.x;
        acc[r] += w4.y * h4.y;
        acc[r] += w4.z * h4.z;
        acc[r] += w4.w * h4.w;
      }
    }

    // prefetch next x row (known in advance, unlike h)
    {
      const int tn = (t + 1 < TSTEPS) ? (t + 1) : 0;
      xr = *(const float2*)(x + (long)tn * FEAT + 2 * ln);
    }

    // reduce each gate pre-activation across 64 lanes
    #pragma unroll
    for (int r = 0; r < 8; ++r) {
      float a = acc[r];
      a += __shfl_xor(a, 1);
      a += __shfl_xor(a, 2);
      a += __shfl_xor(a, 4);
      a += __shfl_xor(a, 8);
      a += __shfl_xor(a, 16);
      a += __shfl_xor(a, 32);
      acc[r] = a + bias[r];
    }

    // LSTM cell for this wave's 2 hidden units (all lanes redundant)
    const float i0 = sigm(acc[0]),  i1 = sigm(acc[1]);
    const float f0 = sigm(acc[2]),  f1 = sigm(acc[3]);
    const float g0 = tanh_(acc[4]), g1 = tanh_(acc[5]);
    const float o0 = sigm(acc[6]),  o1 = sigm(acc[7]);
    c0 = f0 * c0 + i0 * g0;
    c1 = f1 * c1 + i1 * g1;
    const float h0 = o0 * tanh_(c0);
    const float h1 = o1 * tanh_(c1);

    if (ln == 0) {
      float* hdst = ((t + 1) & 1) ? hbuf1 : hbuf0;
      F2U hv2; hv2.f = make_float2(h0, h1);
      __hip_atomic_store((unsigned long long*)(hdst + j0), hv2.u,
                         __ATOMIC_RELAXED, __HIP_MEMORY_SCOPE_AGENT);
      __hip_atomic_fetch_add(myleaf, 1u, __ATOMIC_RELEASE,
                             __HIP_MEMORY_SCOPE_AGENT);
    }
  }

  // ---- head phase 1: ylin[j] = b_lin[j] + sum_k W_lin[j,k]*h_final[k] ----
  {
    const float* hsrc = hbuf0;   // h_8192 lives in parity-0 buffer
    float4 hv[8];
    if (wv == 0) {
      const unsigned target = 128u * (unsigned)(TSTEPS + 1);
      const unsigned* lp = leaves + (ln & 7) * 64;
      while (true) {
        unsigned v = __hip_atomic_load(lp, __ATOMIC_RELAXED,
                                       __HIP_MEMORY_SCOPE_AGENT);
        if (__all(v >= target)) break;
      }
      __builtin_amdgcn_fence(__ATOMIC_ACQUIRE, "agent");
      #pragma unroll
      for (int k = 0; k < 8; ++k) {
        F2U lo, hi;
        const float* p = hsrc + 4 * (ln + 64 * k);
        lo.u = __hip_atomic_load((const unsigned long long*)p,
                                 __ATOMIC_RELAXED, __HIP_MEMORY_SCOPE_AGENT);
        hi.u = __hip_atomic_load((const unsigned long long*)(p + 2),
                                 __ATOMIC_RELAXED, __HIP_MEMORY_SCOPE_AGENT);
        hv[k] = make_float4(lo.f.x, lo.f.y, hi.f.x, hi.f.y);
        *(float4*)&h_lds[0][4 * (ln + 64 * k)] = hv[k];
      }
    }
    __syncthreads();
    if (wv != 0) {
      #pragma unroll
      for (int k = 0; k < 8; ++k)
        hv[k] = *(const float4*)&h_lds[0][4 * (ln + 64 * k)];
    }

    float a0 = 0.0f, a1 = 0.0f;
    const float* wl0 = W_lin + (long)j0 * H;
    const float* wl1 = W_lin + (long)(j0 + 1) * H;
    #pragma unroll
    for (int k = 0; k < 8; ++k) {
      const float4 h4 = hv[k];
      const float4 u0 = *(const float4*)(wl0 + 4 * (ln + 64 * k));
      const float4 u1 = *(const float4*)(wl1 + 4 * (ln + 64 * k));
      a0 += u0.x * h4.x + u0.y * h4.y + u0.z * h4.z + u0.w * h4.w;
      a1 += u1.x * h4.x + u1.y * h4.y + u1.z * h4.z + u1.w * h4.w;
    }
    a0 += __shfl_xor(a0, 1);  a0 += __shfl_xor(a0, 2);  a0 += __shfl_xor(a0, 4);
    a0 += __shfl_xor(a0, 8);  a0 += __shfl_xor(a0, 16); a0 += __shfl_xor(a0, 32);
    a1 += __shfl_xor(a1, 1);  a1 += __shfl_xor(a1, 2);  a1 += __shfl_xor(a1, 4);
    a1 += __shfl_xor(a1, 8);  a1 += __shfl_xor(a1, 16); a1 += __shfl_xor(a1, 32);

    if (ln == 0) {
      F2U yv; yv.f = make_float2(a0 + b_lin[j0], a1 + b_lin[j0 + 1]);
      __hip_atomic_store((unsigned long long*)(ylin + j0), yv.u,
                         __ATOMIC_RELAXED, __HIP_MEMORY_SCOPE_AGENT);
      __hip_atomic_fetch_add(myleaf, 1u, __ATOMIC_RELEASE,
                             __HIP_MEMORY_SCOPE_AGENT);
    }
  }

  // ---- head phase 2: y = ylin @ W_out.T + b_out (block 0, wave 0 only) ----
  if (b == 0 && wv == 0) {
    const unsigned target = 128u * (unsigned)(TSTEPS + 2);
    const unsigned* lp = leaves + (ln & 7) * 64;
    while (true) {
      unsigned v = __hip_atomic_load(lp, __ATOMIC_RELAXED,
                                     __HIP_MEMORY_SCOPE_AGENT);
      if (__all(v >= target)) break;
    }
    __builtin_amdgcn_fence(__ATOMIC_ACQUIRE, "agent");
    float p0 = 0.0f, p1 = 0.0f;
    #pragma unroll
    for (int k = 0; k < 8; ++k) {
      const int c = 4 * (ln + 64 * k);
      const float4 yv = *(const float4*)(ylin + c);
      const float4 q0 = *(const float4*)(W_out + c);
      const float4 q1 = *(const float4*)(W_out + H + c);
      p0 += q0.x * yv.x + q0.y * yv.y + q0.z * yv.z + q0.w * yv.w;
      p1 += q1.x * yv.x + q1.y * yv.y + q1.z * yv.z + q1.w * yv.w;
    }
    p0 += __shfl_xor(p0, 1);  p0 += __shfl_xor(p0, 2);  p0 += __shfl_xor(p0, 4);
    p0 += __shfl_xor(p0, 8);  p0 += __shfl_xor(p0, 16); p0 += __shfl_xor(p0, 32);
    p1 += __shfl_xor(p1, 1);  p1 += __shfl_xor(p1, 2);  p1 += __shfl_xor(p1, 4);
    p1 += __shfl_xor(p1, 8);  p1 += __shfl_xor(p1, 16); p1 += __shfl_xor(p1, 32);
    if (ln == 0) {
      out[0] = p0 + b_out[0];
      out[1] = p1 + b_out[1];
    }
  }
}

extern "C" void kernel_launch(void* const* d_in, const int* in_sizes, int n_in,
                              void* d_out, int out_size, void* d_ws, size_t ws_size,
                              hipStream_t stream) {
  const float* x     = (const float*)d_in[0];
  const float* W_ih  = (const float*)d_in[1];
  const float* W_hh  = (const float*)d_in[2];
  const float* b_ih  = (const float*)d_in[3];
  const float* b_hh  = (const float*)d_in[4];
  const float* W_lin = (const float*)d_in[5];
  const float* b_lin = (const float*)d_in[6];
  const float* W_out = (const float*)d_in[7];
  const float* b_out = (const float*)d_in[8];

  lstm_persist<<<dim3(NBLK), dim3(NTHR), 0, stream>>>(
      x, W_ih, W_hh, b_ih, b_hh, W_lin, b_lin, W_out, b_out,
      (float*)d_out, (float*)d_ws);
}